// Round 16
// baseline (430.816 us; speedup 1.0000x reference)
//
#include <hip/hip_runtime.h>
#include <hip/hip_bf16.h>
#include <stdint.h>

// Problem constants
#define DM   1024
#define NH   16
#define DH   64
#define BATCH 4
#define SEQ  2048
#define MROWS (BATCH*SEQ)   // 8192

typedef float f32x4 __attribute__((ext_vector_type(4)));
typedef __bf16 bf16x8 __attribute__((ext_vector_type(8)));
typedef short s16x4 __attribute__((ext_vector_type(4)));
typedef int   i32x2 __attribute__((ext_vector_type(2)));

// Q is pre-scaled by (1/sqrt(D)) * log2(e) so softmax can use exp2 directly.
#define QSCALE 0.045084220f

#define VM(n) asm volatile("s_waitcnt vmcnt(" #n ")" ::: "memory")
#define LGKM0 do { asm volatile("s_waitcnt lgkmcnt(0)" ::: "memory"); \
                   __builtin_amdgcn_sched_barrier(0); } while (0)

__device__ __forceinline__ short f2bs(float f) {
    __bf16 h = (__bf16)f;
    return __builtin_bit_cast(short, h);
}

__device__ __forceinline__ void gload_lds16(const void* g, void* l) {
    __builtin_amdgcn_global_load_lds(
        (__attribute__((address_space(1))) void*)(g),
        (__attribute__((address_space(3))) void*)(l), 16, 0, 0);
}

// XCD-chunked bijective swizzle (grid % 8 == 0), n-tile fastest within chunk.
__device__ __forceinline__ void swz_xy(int ny, int& x, int& y) {
    const int bid = blockIdx.x;
    const int cpx = gridDim.x >> 3;
    const int wg  = (bid & 7) * cpx + (bid >> 3);
    x = wg / ny;
    y = wg % ny;
}

// ---------------------------------------------------------------------------
// Transpose + fp32->bf16 convert: wt[n][k] = bf16(w[k][n]).  64x64 tiles.
// ---------------------------------------------------------------------------
__global__ __launch_bounds__(256) void transpose_cvt_kernel(
    const float* __restrict__ w, short* __restrict__ wt, int K, int N)
{
    __shared__ short tile[64 * 65];
    const int k0 = blockIdx.x * 64, n0 = blockIdx.y * 64;
    const int t = threadIdx.x;
#pragma unroll
    for (int i = 0; i < 16; ++i) {
        int idx = i * 256 + t;
        int r = idx >> 6, c = idx & 63;
        tile[r * 65 + c] = f2bs(w[(size_t)(k0 + r) * N + n0 + c]);
    }
    __syncthreads();
#pragma unroll
    for (int i = 0; i < 16; ++i) {
        int idx = i * 256 + t;
        int r = idx >> 6, c = idx & 63;      // r: n-local, c: k-local
        wt[(size_t)(n0 + r) * K + k0 + c] = tile[c * 65 + r];
    }
}

// ---------------------------------------------------------------------------
// LayerNorm (rows of 1024 fp32) -> bf16
// ---------------------------------------------------------------------------
__global__ __launch_bounds__(256) void ln_kernel(
    const float* __restrict__ x, const float* __restrict__ g,
    const float* __restrict__ be, short* __restrict__ out)
{
    const int row = blockIdx.x, t = threadIdx.x;
    const float4 v = ((const float4*)(x + (size_t)row * DM))[t];
    float s  = v.x + v.y + v.z + v.w;
    float ss = v.x * v.x + v.y * v.y + v.z * v.z + v.w * v.w;
#pragma unroll
    for (int d = 1; d < 64; d <<= 1) {
        s  += __shfl_xor(s, d, 64);
        ss += __shfl_xor(ss, d, 64);
    }
    __shared__ float red[8];
    const int wid = t >> 6;
    if ((t & 63) == 0) { red[wid] = s; red[wid + 4] = ss; }
    __syncthreads();
    s  = red[0] + red[1] + red[2] + red[3];
    ss = red[4] + red[5] + red[6] + red[7];
    const float mu = s * (1.0f / DM);
    const float rs = rsqrtf(ss * (1.0f / DM) - mu * mu + 1e-5f);
    const float4 gg = ((const float4*)g)[t];
    const float4 bb = ((const float4*)be)[t];
    short4 o;
    o.x = f2bs((v.x - mu) * rs * gg.x + bb.x);
    o.y = f2bs((v.y - mu) * rs * gg.y + bb.y);
    o.z = f2bs((v.z - mu) * rs * gg.z + bb.z);
    o.w = f2bs((v.w - mu) * rs * gg.w + bb.w);
    ((short4*)(out + (size_t)row * DM))[t] = o;
}

// ---------------------------------------------------------------------------
// Staging: rows x 32-short K-slab (512-thread GEMMs).  LDS linear; global
// source pre-swizzled (slot s holds linear slot s ^ ((row>>1)&3)).
// ---------------------------------------------------------------------------
template<int NCHUNK>   // 16B chunks per tile: rows*4
__device__ __forceinline__ void stage32(
    const short* __restrict__ G, int ldk, int row0, int k0,
    short* __restrict__ lds, int t)
{
#pragma unroll
    for (int i = 0; i < NCHUNK / 512; ++i) {
        const int c  = i * 512 + t;
        const int r  = c >> 2;
        const int sl = (c & 3) ^ ((r >> 1) & 3);
        gload_lds16(&G[(size_t)(row0 + r) * ldk + k0 + sl * 8], &lds[c * 8]);
    }
}

// ---------------------------------------------------------------------------
// 256x256 GEMM, BK=32, 4-buffer depth-3 prefetch, TWO 16-MFMA phases per
// K-step, counted vmcnt at phase B only.  8 waves (2M x 4N).
// EPI 0: QKV scatter (K and V^T stored PRE-SWIZZLED for attn LDS staging).
// EPI 2: relu(acc+bias) -> bf16.
// ---------------------------------------------------------------------------
template<int EPI>
__global__ __launch_bounds__(512) void gemm256(
    const short* __restrict__ A, const short* __restrict__ Bt,
    int N, int K, int nyT,
    const float* __restrict__ bias, short* __restrict__ outb,
    short* __restrict__ qo, short* __restrict__ ko, short* __restrict__ vo)
{
    __shared__ short As[4][8192];
    __shared__ short Bs[4][8192];
    const int t = threadIdx.x, lane = t & 63, w = t >> 6;
    const int l15 = lane & 15, hi = lane >> 4;
    const int wm = (w >> 2) * 128, wn = (w & 3) * 64;
    int bx, by; swz_xy(nyT, bx, by);
    const int m0 = bx * 256, n0 = by * 256;
    const int NT = K >> 5;

    f32x4 acc[8][4] = {};

    stage32<1024>(A, K, m0, 0,  As[0], t); stage32<1024>(Bt, K, n0, 0,  Bs[0], t);
    stage32<1024>(A, K, m0, 32, As[1], t); stage32<1024>(Bt, K, n0, 32, Bs[1], t);
    stage32<1024>(A, K, m0, 64, As[2], t); stage32<1024>(Bt, K, n0, 64, Bs[2], t);
    VM(8);                              // tile 0 (A,B) landed
    __builtin_amdgcn_s_barrier();

    for (int kt = 0; kt < NT; ++kt) {
        const short* Ac = As[kt & 3];
        const short* Bc = Bs[kt & 3];
        const int k3 = (kt + 3) << 5;
        bf16x8 af[8], bfr[4];

        // ---- phase A: fm 0..3 ; stage A(kt+3) ----
#pragma unroll
        for (int fm = 0; fm < 4; ++fm) {
            const int r = wm + fm * 16 + l15;
            af[fm] = *(const bf16x8*)&Ac[r * 32 + ((hi ^ ((r >> 1) & 3)) << 3)];
        }
#pragma unroll
        for (int fn = 0; fn < 4; ++fn) {
            const int r = wn + fn * 16 + l15;
            bfr[fn] = *(const bf16x8*)&Bc[r * 32 + ((hi ^ ((r >> 1) & 3)) << 3)];
        }
        if (kt + 3 < NT) stage32<1024>(A, K, m0, k3, As[(kt + 3) & 3], t);
        __builtin_amdgcn_s_barrier();
        LGKM0;
        __builtin_amdgcn_s_setprio(1);
#pragma unroll
        for (int fm = 0; fm < 4; ++fm)
#pragma unroll
            for (int fn = 0; fn < 4; ++fn)
                acc[fm][fn] = __builtin_amdgcn_mfma_f32_16x16x32_bf16(
                    af[fm], bfr[fn], acc[fm][fn], 0, 0, 0);
        __builtin_amdgcn_s_setprio(0);
        __builtin_amdgcn_s_barrier();

        // ---- phase B: fm 4..7 ; stage B(kt+3) ; counted vmcnt ----
#pragma unroll
        for (int fm = 4; fm < 8; ++fm) {
            const int r = wm + fm * 16 + l15;
            af[fm] = *(const bf16x8*)&Ac[r * 32 + ((hi ^ ((r >> 1) & 3)) << 3)];
        }
        if (kt + 3 < NT) {
            stage32<1024>(Bt, K, n0, k3, Bs[(kt + 3) & 3], t);
            VM(8);
        } else if (kt + 2 < NT) VM(4);
        else if (kt + 1 < NT) VM(0);
        __builtin_amdgcn_s_barrier();
        LGKM0;
        __builtin_amdgcn_s_setprio(1);
#pragma unroll
        for (int fm = 4; fm < 8; ++fm)
#pragma unroll
            for (int fn = 0; fn < 4; ++fn)
                acc[fm][fn] = __builtin_amdgcn_mfma_f32_16x16x32_bf16(
                    af[fm], bfr[fn], acc[fm][fn], 0, 0, 0);
        __builtin_amdgcn_s_setprio(0);
        __builtin_amdgcn_s_barrier();
    }

#pragma unroll
    for (int fm = 0; fm < 8; ++fm)
#pragma unroll
        for (int fn = 0; fn < 4; ++fn) {
            const int row0 = m0 + wm + fm * 16 + hi * 4;
            const int nn = n0 + wn + fn * 16 + l15;
            const f32x4 a = acc[fm][fn];
            if constexpr (EPI == 0) {
                const int mat = nn >> 10, n1 = nn & 1023;
                const int head = n1 >> 6, dh = n1 & 63;
                if (mat == 2) {
                    // V^T store, tok-granule swizzled by (dh&7)
                    const int tok = row0 & 2047, b = row0 >> 11;
                    const int tokp = (tok & ~63) |
                        (((((tok >> 3) & 7) ^ (dh & 7)) << 3)) | (tok & 7);
                    short4 pk;
                    pk.x = f2bs(a[0]); pk.y = f2bs(a[1]);
                    pk.z = f2bs(a[2]); pk.w = f2bs(a[3]);
                    *(short4*)&vo[((size_t)(b * NH + head) * DH + dh) * SEQ + tokp] = pk;
                } else if (mat == 1) {
                    // K store, dh-granule swizzled by (tok&7)
#pragma unroll
                    for (int rr = 0; rr < 4; ++rr) {
                        const int m = row0 + rr;
                        const int b = m >> 11, tok = m & 2047;
                        const int dhp = (((dh >> 3) ^ (tok & 7)) << 3) | (dh & 7);
                        ko[((size_t)(b * NH + head) * SEQ + tok) * DH + dhp] =
                            f2bs(a[rr]);
                    }
                } else {
#pragma unroll
                    for (int rr = 0; rr < 4; ++rr) {
                        const int m = row0 + rr;
                        const int b = m >> 11, tok = m & 2047;
                        qo[((size_t)(b * NH + head) * SEQ + tok) * DH + dh] =
                            f2bs(a[rr] * QSCALE);
                    }
                }
            } else {
                const float bb = bias[nn];
#pragma unroll
                for (int rr = 0; rr < 4; ++rr) {
                    const float z = a[rr] + bb;
                    outb[(size_t)(row0 + rr) * N + nn] = f2bs(z > 0.f ? z : 0.f);
                }
            }
        }
}

// ---------------------------------------------------------------------------
// WIDE-WAVE GEMM for N=1024 (proj, FFN2): block 256x64, TWO waves, each wave
// C = 128x64 (af[8]+bfr[4] = 12 ds_read : 32 MFMA -> 1.33x less LDS traffic
// per FLOP than 64x64 waves; r15 counters show bt128 LDS-read-bound at 87%).
// BK=32, triple-buffered depth-2, compiler-scheduled single phase.
// Ledger: 10 gloads/thread/tile (A 8 + B 2); prologue 3 tiles (30 out);
// top VM(20) = tile kt landed; tail VM(10)/VM(0); bottom stage(kt+3) into
// buf kt%3 whose reads completed (MFMA deps) before the bottom barrier.
// LDS 3 x (16K + 4K) = 60 KB -> 2 blocks/CU.
// EPI: out fp32 = acc + bias[n] + res[m,n]
// ---------------------------------------------------------------------------
__global__ __launch_bounds__(128) void gemm_wide(
    const short* __restrict__ A, const short* __restrict__ Bt,
    int N, int K, int nyT,
    const float* __restrict__ bias, const float* __restrict__ res,
    float* __restrict__ outf)
{
    __shared__ short As[3][8192];    // 256 x 32
    __shared__ short Bs[3][2048];    // 64 x 32
    const int t = threadIdx.x, lane = t & 63, w = t >> 6;   // w = 0,1
    const int l15 = lane & 15, hi = lane >> 4;
    const int wm = w * 128;
    int bx, by; swz_xy(nyT, bx, by);
    const int m0 = bx * 256, n0 = by * 64;
    const int NT = K >> 5;

    f32x4 acc[8][4] = {};

#define STAGEW(k0, buf)                                                       \
    do {                                                                      \
        _Pragma("unroll")                                                     \
        for (int i2 = 0; i2 < 8; ++i2) {                                      \
            const int c  = i2 * 128 + t;                                      \
            const int r  = c >> 2;                                            \
            const int sl = (c & 3) ^ ((r >> 1) & 3);                          \
            gload_lds16(&A[(size_t)(m0 + r) * K + (k0) + sl * 8],             \
                        &As[buf][c * 8]);                                     \
        }                                                                     \
        _Pragma("unroll")                                                     \
        for (int i2 = 0; i2 < 2; ++i2) {                                      \
            const int c  = i2 * 128 + t;                                      \
            const int r  = c >> 2;                                            \
            const int sl = (c & 3) ^ ((r >> 1) & 3);                          \
            gload_lds16(&Bt[(size_t)(n0 + r) * K + (k0) + sl * 8],            \
                        &Bs[buf][c * 8]);                                     \
        }                                                                     \
    } while (0)

    STAGEW(0, 0); STAGEW(32, 1); STAGEW(64, 2);

    for (int kt = 0; kt < NT; ++kt) {
        if (kt + 2 < NT) VM(20);
        else if (kt + 1 < NT) VM(10);
        else VM(0);
        __builtin_amdgcn_s_barrier();     // tile kt visible to all waves

        const short* Ac = As[kt % 3];
        const short* Bc = Bs[kt % 3];
        bf16x8 af[8], bfr[4];
#pragma unroll
        for (int fm = 0; fm < 8; ++fm) {
            const int r = wm + fm * 16 + l15;
            af[fm] = *(const bf16x8*)&Ac[r * 32 + ((hi ^ ((r >> 1) & 3)) << 3)];
        }
#pragma unroll
        for (int fn = 0; fn < 4; ++fn) {
            const int r = fn * 16 + l15;
            bfr[fn] = *(const bf16x8*)&Bc[r * 32 + ((hi ^ ((r >> 1) & 3)) << 3)];
        }
#pragma unroll
        for (int fm = 0; fm < 8; ++fm)
#pragma unroll
            for (int fn = 0; fn < 4; ++fn)
                acc[fm][fn] = __builtin_amdgcn_mfma_f32_16x16x32_bf16(
                    af[fm], bfr[fn], acc[fm][fn], 0, 0, 0);

        __builtin_amdgcn_s_barrier();     // all reads of kt done (MFMA deps)
        if (kt + 3 < NT) STAGEW((kt + 3) << 5, kt % 3);
    }
#undef STAGEW

#pragma unroll
    for (int fm = 0; fm < 8; ++fm)
#pragma unroll
        for (int fn = 0; fn < 4; ++fn) {
            const int row0 = m0 + wm + fm * 16 + hi * 4;
            const int nn = n0 + fn * 16 + l15;
            const float bb = bias[nn];
            const f32x4 a = acc[fm][fn];
#pragma unroll
            for (int rr = 0; rr < 4; ++rr) {
                const int m = row0 + rr;
                outf[(size_t)m * N + nn] = a[rr] + bb + res[(size_t)m * N + nn];
            }
        }
}

// ---------------------------------------------------------------------------
// Causal flash attention v6: 8-wave blocks, double-tile staging (one barrier
// per 2 KV tiles).  Unchanged from r15.
// ---------------------------------------------------------------------------
__global__ __launch_bounds__(512) void attn_kernel(
    const short* __restrict__ Q, const short* __restrict__ Kx,
    const short* __restrict__ Vt, short* __restrict__ att)
{
    __shared__ short Ks[2][2][4096];
    __shared__ short Vs[2][2][4096];

    const int n  = blockIdx.x;
    const int bh = n & 63;
    const int j  = n >> 6;                    // 0..7
    const int qb = (j < 4) ? (7 - j) : (j - 4);
    const int tid = threadIdx.x;
    const int lane = tid & 63;
    const int wq = tid >> 6;                  // 0..7
    const int l15 = lane & 15, hi = lane >> 4;
    const int qw = qb * 256 + wq * 32;
    const size_t base  = (size_t)bh * (SEQ * DH);   // Q,K: [bh][tok][dh]
    const size_t vbase = (size_t)bh * (DH * SEQ);   // Vt:  [bh][dh][tok]
    const int b = bh >> 4, head = bh & 15;

    // Q fragments (B-operand): [q=l15][k=hi*8..+7]
    bf16x8 qf[2][2];
#pragma unroll
    for (int mf = 0; mf < 2; ++mf)
#pragma unroll
        for (int kf = 0; kf < 2; ++kf)
            qf[mf][kf] = *(const bf16x8*)
                &Q[base + (size_t)(qw + mf * 16 + l15) * DH + kf * 32 + hi * 8];

    f32x4 O[2][4] = {};
    float L[2] = {0.f, 0.f};

    const int nkv_blk = 4 * qb + 4;           // tiles staged by the block
    const int ndt     = nkv_blk >> 1;         // double-tiles
    const int nkv_wv  = (qw + 95) >> 6;       // tiles this wave computes

    // ---- stage a DOUBLE tile (128 kv rows): 4 loads/thread ----
#define STAGE_KV2(DT, BUF)                                                     \
    do {                                                                       \
        const int kvo = (DT) * 128;                                            \
        const int rw = tid >> 3, sl = tid & 7;                                 \
        _Pragma("unroll")                                                      \
        for (int sb = 0; sb < 2; ++sb) {                                       \
            gload_lds16(&Kx[base + (size_t)(kvo + sb * 64 + rw) * DH + sl * 8],\
                        &Ks[BUF][sb][tid * 8]);                                \
            gload_lds16(&Vt[vbase + (size_t)rw * SEQ + kvo + sb * 64 + sl * 8],\
                        &Vs[BUF][sb][tid * 8]);                                \
        }                                                                      \
    } while (0)

    STAGE_KV2(0, 0);

    for (int dt = 0; dt < ndt; ++dt) {
        VM(0);                               // this wave's staged loads landed
        __builtin_amdgcn_s_barrier();        // all waves' loads landed
        if (dt + 1 < ndt) STAGE_KV2(dt + 1, (dt + 1) & 1);

#pragma unroll
        for (int sb = 0; sb < 2; ++sb) {
            const int t2 = dt * 2 + sb;
            if (t2 >= nkv_wv) break;
            const short* Kc = &Ks[dt & 1][sb][0];
            const short* Vc = &Vs[dt & 1][sb][0];
            const int kv0 = t2 * 64;

            // K fragments (A-operand): row = kv-local, swizzled read
            bf16x8 kfr[4][2];
#pragma unroll
            for (int nf = 0; nf < 4; ++nf)
#pragma unroll
                for (int kf = 0; kf < 2; ++kf)
                    kfr[nf][kf] = *(const bf16x8*)
                        &Kc[(nf * 16 + l15) * 64 + (((kf * 4 + hi) ^ (l15 & 7)) << 3)];

            // St[kv][q] = K . Q^T  (swapped)
            f32x4 St[4][2] = {};
#pragma unroll
            for (int kf = 0; kf < 2; ++kf)
#pragma unroll
                for (int nf = 0; nf < 4; ++nf)
#pragma unroll
                    for (int mf = 0; mf < 2; ++mf)
                        St[nf][mf] = __builtin_amdgcn_mfma_f32_16x16x32_bf16(
                            kfr[nf][kf], qf[mf][kf], St[nf][mf], 0, 0, 0);

            if (kv0 + 63 > qw) {   // causal tail masking
#pragma unroll
                for (int mf = 0; mf < 2; ++mf) {
                    const int q = qw + mf * 16 + l15;
#pragma unroll
                    for (int nf = 0; nf < 4; ++nf)
#pragma unroll
                        for (int r = 0; r < 4; ++r) {
                            const int kv = kv0 + nf * 16 + hi * 4 + r;
                            if (kv > q) St[nf][mf][r] = -3.0e38f;
                        }
                }
            }

            // P = exp2(St); per-tile partial L; pack to bf16 A-frags in regs
            float lp[2] = {0.f, 0.f};
            s16x4 pa[4][2];
#pragma unroll
            for (int nf = 0; nf < 4; ++nf)
#pragma unroll
                for (int mf = 0; mf < 2; ++mf) {
                    const float p0 = exp2f(St[nf][mf][0]);
                    const float p1 = exp2f(St[nf][mf][1]);
                    const float p2 = exp2f(St[nf][mf][2]);
                    const float p3 = exp2f(St[nf][mf][3]);
                    lp[mf] += (p0 + p1) + (p2 + p3);
                    unsigned dw0, dw1;
                    asm("v_cvt_pk_bf16_f32 %0, %1, %2" : "=v"(dw0) : "v"(p0), "v"(p1));
                    asm("v_cvt_pk_bf16_f32 %0, %1, %2" : "=v"(dw1) : "v"(p2), "v"(p3));
                    i32x2 dd; dd[0] = (int)dw0; dd[1] = (int)dw1;
                    pa[nf][mf] = __builtin_bit_cast(s16x4, dd);
                }
            L[0] += lp[0]; L[1] += lp[1];

            // PV: O[q][d] += P . V  (16x16x16, A = pa regs, B = V^T in LDS)
#pragma unroll
            for (int nf = 0; nf < 4; ++nf)
#pragma unroll
                for (int jf = 0; jf < 4; ++jf) {
                    const s16x4 vfr = *(const s16x4*)
                        &Vc[(jf * 16 + l15) * 64 +
                            ((((nf * 2 + (hi >> 1)) ^ (l15 & 7)) << 3) + ((hi & 1) << 2))];
#pragma unroll
                    for (int mf = 0; mf < 2; ++mf)
                        O[mf][jf] = __builtin_amdgcn_mfma_f32_16x16x16bf16_1k(
                            pa[nf][mf], vfr, O[mf][jf], 0, 0, 0);
                }
        }
    }
#undef STAGE_KV2

    // L: reduce across hi groups (lane holds L for q = qw + mf*16 + l15)
#pragma unroll
    for (int mf = 0; mf < 2; ++mf) {
        L[mf] += __shfl_xor(L[mf], 16, 64);
        L[mf] += __shfl_xor(L[mf], 32, 64);
    }
    const float inv0 = 1.0f / L[0], inv1 = 1.0f / L[1];

    // redistribute 1/L from col-space (l15=q) to row-space (hi*4+r=q)
#pragma unroll
    for (int mf = 0; mf < 2; ++mf) {
        const float invm = mf ? inv1 : inv0;
#pragma unroll
        for (int r = 0; r < 4; ++r) {
            const int addr = ((lane >> 4) << 4) + (r << 2);   // 4*(hi*4+r)
            const float iv = __builtin_bit_cast(float,
                __builtin_amdgcn_ds_bpermute(addr, __builtin_bit_cast(int, invm)));
            const int q = qw + mf * 16 + hi * 4 + r;
#pragma unroll
            for (int jf = 0; jf < 4; ++jf)
                att[(size_t)(b * SEQ + q) * DM + head * DH + jf * 16 + l15] =
                    f2bs(O[mf][jf][r] * iv);
        }
    }
}

// ---------------------------------------------------------------------------
extern "C" void kernel_launch(void* const* d_in, const int* in_sizes, int n_in,
                              void* d_out, int out_size, void* d_ws, size_t ws_size,
                              hipStream_t stream) {
    const float* x   = (const float*)d_in[0];
    const float* wq  = (const float*)d_in[1];
    const float* wk  = (const float*)d_in[2];
    const float* wv  = (const float*)d_in[3];
    const float* wp  = (const float*)d_in[4];
    const float* bp  = (const float*)d_in[5];
    const float* w1  = (const float*)d_in[6];
    const float* b1  = (const float*)d_in[7];
    const float* w2  = (const float*)d_in[8];
    const float* b2  = (const float*)d_in[9];
    const float* g1  = (const float*)d_in[10];
    const float* be1 = (const float*)d_in[11];
    const float* g2  = (const float*)d_in[12];
    const float* be2 = (const float*)d_in[13];
    float* out = (float*)d_out;

    char* ws = (char*)d_ws;
    short* wqkv_t = (short*)(ws + 0);          //  6.0 MB  [3072][1024]
    short* wp_t   = (short*)(ws + 6291456);    //  2.0 MB  [1024][1024]
    short* w1_t   = (short*)(ws + 8388608);    //  8.0 MB  [4096][1024]
    short* w2_t   = (short*)(ws + 16777216);   //  8.0 MB  [1024][4096]
    short* h      = (short*)(ws + 25165824);   // 16 MB
    short* qb     = (short*)(ws + 41943040);   // 16 MB
    short* kb     = (short*)(ws + 58720256);   // 16 MB
    short* vb     = (short*)(ws + 75497472);   // 16 MB
    short* att    = (short*)(ws + 92274688);   // 16 MB
    float* x1     = (float*)(ws + 109051904);  // 32 MB
    short* h2     = (short*)(ws + 142606336);  // 16 MB
    short* tbuf   = (short*)(ws + 25165824);   // 64 MB, aliases h/qb/kb/vb (dead)

    dim3 blk(256);

    transpose_cvt_kernel<<<dim3(16, 16), blk, 0, stream>>>(wq, wqkv_t,                1024, 1024);
    transpose_cvt_kernel<<<dim3(16, 16), blk, 0, stream>>>(wk, wqkv_t + 1024 * 1024,  1024, 1024);
    transpose_cvt_kernel<<<dim3(16, 16), blk, 0, stream>>>(wv, wqkv_t + 2048 * 1024,  1024, 1024);
    transpose_cvt_kernel<<<dim3(16, 16), blk, 0, stream>>>(wp, wp_t,                  1024, 1024);
    transpose_cvt_kernel<<<dim3(16, 64), blk, 0, stream>>>(w1, w1_t,                  1024, 4096);
    transpose_cvt_kernel<<<dim3(64, 16), blk, 0, stream>>>(w2, w2_t,                  4096, 1024);

    ln_kernel<<<MROWS, blk, 0, stream>>>(x, g1, be1, h);

    gemm256<0><<<dim3(384), dim3(512), 0, stream>>>(h, wqkv_t, 3072, 1024, 12,
        nullptr, nullptr, qb, kb, vb);

    attn_kernel<<<dim3(512), dim3(512), 0, stream>>>(qb, kb, vb, att);

    gemm_wide<<<dim3(512), dim3(128), 0, stream>>>(att, wp_t, 1024, 1024, 16,
        bp, x, x1);

    ln_kernel<<<MROWS, blk, 0, stream>>>(x1, g2, be2, h2);

    gemm256<2><<<dim3(512), dim3(512), 0, stream>>>(h2, w1_t, 4096, 1024, 16,
        b1, tbuf, nullptr, nullptr, nullptr);

    gemm_wide<<<dim3(512), dim3(128), 0, stream>>>(tbuf, w2_t, 1024, 4096, 16,
        b2, x1, out);
}

// Round 17
// 367.575 us; speedup vs baseline: 1.1720x; 1.1720x over previous
//
#include <hip/hip_runtime.h>
#include <hip/hip_bf16.h>
#include <stdint.h>

// Problem constants
#define DM   1024
#define NH   16
#define DH   64
#define BATCH 4
#define SEQ  2048
#define MROWS (BATCH*SEQ)   // 8192

typedef float f32x4 __attribute__((ext_vector_type(4)));
typedef __bf16 bf16x8 __attribute__((ext_vector_type(8)));
typedef short s16x4 __attribute__((ext_vector_type(4)));
typedef int   i32x2 __attribute__((ext_vector_type(2)));

// Q is pre-scaled by (1/sqrt(D)) * log2(e) so softmax can use exp2 directly.
#define QSCALE 0.045084220f

#define VM(n) asm volatile("s_waitcnt vmcnt(" #n ")" ::: "memory")
#define LGKM0 do { asm volatile("s_waitcnt lgkmcnt(0)" ::: "memory"); \
                   __builtin_amdgcn_sched_barrier(0); } while (0)

__device__ __forceinline__ short f2bs(float f) {
    __bf16 h = (__bf16)f;
    return __builtin_bit_cast(short, h);
}

__device__ __forceinline__ void gload_lds16(const void* g, void* l) {
    __builtin_amdgcn_global_load_lds(
        (__attribute__((address_space(1))) void*)(g),
        (__attribute__((address_space(3))) void*)(l), 16, 0, 0);
}

// XCD-chunked bijective swizzle (grid % 8 == 0), n-tile fastest within chunk.
__device__ __forceinline__ void swz_xy(int ny, int& x, int& y) {
    const int bid = blockIdx.x;
    const int cpx = gridDim.x >> 3;
    const int wg  = (bid & 7) * cpx + (bid >> 3);
    x = wg / ny;
    y = wg % ny;
}

// ---------------------------------------------------------------------------
// Transpose + fp32->bf16 convert: wt[n][k] = bf16(w[k][n]).  64x64 tiles.
// ---------------------------------------------------------------------------
__global__ __launch_bounds__(256) void transpose_cvt_kernel(
    const float* __restrict__ w, short* __restrict__ wt, int K, int N)
{
    __shared__ short tile[64 * 65];
    const int k0 = blockIdx.x * 64, n0 = blockIdx.y * 64;
    const int t = threadIdx.x;
#pragma unroll
    for (int i = 0; i < 16; ++i) {
        int idx = i * 256 + t;
        int r = idx >> 6, c = idx & 63;
        tile[r * 65 + c] = f2bs(w[(size_t)(k0 + r) * N + n0 + c]);
    }
    __syncthreads();
#pragma unroll
    for (int i = 0; i < 16; ++i) {
        int idx = i * 256 + t;
        int r = idx >> 6, c = idx & 63;      // r: n-local, c: k-local
        wt[(size_t)(n0 + r) * K + k0 + c] = tile[c * 65 + r];
    }
}

// ---------------------------------------------------------------------------
// LayerNorm (rows of 1024 fp32) -> bf16
// ---------------------------------------------------------------------------
__global__ __launch_bounds__(256) void ln_kernel(
    const float* __restrict__ x, const float* __restrict__ g,
    const float* __restrict__ be, short* __restrict__ out)
{
    const int row = blockIdx.x, t = threadIdx.x;
    const float4 v = ((const float4*)(x + (size_t)row * DM))[t];
    float s  = v.x + v.y + v.z + v.w;
    float ss = v.x * v.x + v.y * v.y + v.z * v.z + v.w * v.w;
#pragma unroll
    for (int d = 1; d < 64; d <<= 1) {
        s  += __shfl_xor(s, d, 64);
        ss += __shfl_xor(ss, d, 64);
    }
    __shared__ float red[8];
    const int wid = t >> 6;
    if ((t & 63) == 0) { red[wid] = s; red[wid + 4] = ss; }
    __syncthreads();
    s  = red[0] + red[1] + red[2] + red[3];
    ss = red[4] + red[5] + red[6] + red[7];
    const float mu = s * (1.0f / DM);
    const float rs = rsqrtf(ss * (1.0f / DM) - mu * mu + 1e-5f);
    const float4 gg = ((const float4*)g)[t];
    const float4 bb = ((const float4*)be)[t];
    short4 o;
    o.x = f2bs((v.x - mu) * rs * gg.x + bb.x);
    o.y = f2bs((v.y - mu) * rs * gg.y + bb.y);
    o.z = f2bs((v.z - mu) * rs * gg.z + bb.z);
    o.w = f2bs((v.w - mu) * rs * gg.w + bb.w);
    ((short4*)(out + (size_t)row * DM))[t] = o;
}

// ---------------------------------------------------------------------------
// Staging: rows x 32-short K-slab (512-thread GEMMs).  LDS linear; global
// source pre-swizzled (slot s holds linear slot s ^ ((row>>1)&3)).
// ---------------------------------------------------------------------------
template<int NCHUNK>   // 16B chunks per tile: rows*4
__device__ __forceinline__ void stage32(
    const short* __restrict__ G, int ldk, int row0, int k0,
    short* __restrict__ lds, int t)
{
#pragma unroll
    for (int i = 0; i < NCHUNK / 512; ++i) {
        const int c  = i * 512 + t;
        const int r  = c >> 2;
        const int sl = (c & 3) ^ ((r >> 1) & 3);
        gload_lds16(&G[(size_t)(row0 + r) * ldk + k0 + sl * 8], &lds[c * 8]);
    }
}

// ---------------------------------------------------------------------------
// 256x256 GEMM, BK=32, 4-buffer depth-3 prefetch, TWO 16-MFMA phases per
// K-step, counted vmcnt at phase B only.  8 waves (2M x 4N).
// EPI 0: QKV scatter (K and V^T stored PRE-SWIZZLED for attn LDS staging).
// EPI 2: relu(acc+bias) -> bf16.
// ---------------------------------------------------------------------------
template<int EPI>
__global__ __launch_bounds__(512) void gemm256(
    const short* __restrict__ A, const short* __restrict__ Bt,
    int N, int K, int nyT,
    const float* __restrict__ bias, short* __restrict__ outb,
    short* __restrict__ qo, short* __restrict__ ko, short* __restrict__ vo)
{
    __shared__ short As[4][8192];
    __shared__ short Bs[4][8192];
    const int t = threadIdx.x, lane = t & 63, w = t >> 6;
    const int l15 = lane & 15, hi = lane >> 4;
    const int wm = (w >> 2) * 128, wn = (w & 3) * 64;
    int bx, by; swz_xy(nyT, bx, by);
    const int m0 = bx * 256, n0 = by * 256;
    const int NT = K >> 5;

    f32x4 acc[8][4] = {};

    stage32<1024>(A, K, m0, 0,  As[0], t); stage32<1024>(Bt, K, n0, 0,  Bs[0], t);
    stage32<1024>(A, K, m0, 32, As[1], t); stage32<1024>(Bt, K, n0, 32, Bs[1], t);
    stage32<1024>(A, K, m0, 64, As[2], t); stage32<1024>(Bt, K, n0, 64, Bs[2], t);
    VM(8);                              // tile 0 (A,B) landed
    __builtin_amdgcn_s_barrier();

    for (int kt = 0; kt < NT; ++kt) {
        const short* Ac = As[kt & 3];
        const short* Bc = Bs[kt & 3];
        const int k3 = (kt + 3) << 5;
        bf16x8 af[8], bfr[4];

        // ---- phase A: fm 0..3 ; stage A(kt+3) ----
#pragma unroll
        for (int fm = 0; fm < 4; ++fm) {
            const int r = wm + fm * 16 + l15;
            af[fm] = *(const bf16x8*)&Ac[r * 32 + ((hi ^ ((r >> 1) & 3)) << 3)];
        }
#pragma unroll
        for (int fn = 0; fn < 4; ++fn) {
            const int r = wn + fn * 16 + l15;
            bfr[fn] = *(const bf16x8*)&Bc[r * 32 + ((hi ^ ((r >> 1) & 3)) << 3)];
        }
        if (kt + 3 < NT) stage32<1024>(A, K, m0, k3, As[(kt + 3) & 3], t);
        __builtin_amdgcn_s_barrier();
        LGKM0;
        __builtin_amdgcn_s_setprio(1);
#pragma unroll
        for (int fm = 0; fm < 4; ++fm)
#pragma unroll
            for (int fn = 0; fn < 4; ++fn)
                acc[fm][fn] = __builtin_amdgcn_mfma_f32_16x16x32_bf16(
                    af[fm], bfr[fn], acc[fm][fn], 0, 0, 0);
        __builtin_amdgcn_s_setprio(0);
        __builtin_amdgcn_s_barrier();

        // ---- phase B: fm 4..7 ; stage B(kt+3) ; counted vmcnt ----
#pragma unroll
        for (int fm = 4; fm < 8; ++fm) {
            const int r = wm + fm * 16 + l15;
            af[fm] = *(const bf16x8*)&Ac[r * 32 + ((hi ^ ((r >> 1) & 3)) << 3)];
        }
        if (kt + 3 < NT) {
            stage32<1024>(Bt, K, n0, k3, Bs[(kt + 3) & 3], t);
            VM(8);
        } else if (kt + 2 < NT) VM(4);
        else if (kt + 1 < NT) VM(0);
        __builtin_amdgcn_s_barrier();
        LGKM0;
        __builtin_amdgcn_s_setprio(1);
#pragma unroll
        for (int fm = 4; fm < 8; ++fm)
#pragma unroll
            for (int fn = 0; fn < 4; ++fn)
                acc[fm][fn] = __builtin_amdgcn_mfma_f32_16x16x32_bf16(
                    af[fm], bfr[fn], acc[fm][fn], 0, 0, 0);
        __builtin_amdgcn_s_setprio(0);
        __builtin_amdgcn_s_barrier();
    }

#pragma unroll
    for (int fm = 0; fm < 8; ++fm)
#pragma unroll
        for (int fn = 0; fn < 4; ++fn) {
            const int row0 = m0 + wm + fm * 16 + hi * 4;
            const int nn = n0 + wn + fn * 16 + l15;
            const f32x4 a = acc[fm][fn];
            if constexpr (EPI == 0) {
                const int mat = nn >> 10, n1 = nn & 1023;
                const int head = n1 >> 6, dh = n1 & 63;
                if (mat == 2) {
                    // V^T store, tok-granule swizzled by (dh&7)
                    const int tok = row0 & 2047, b = row0 >> 11;
                    const int tokp = (tok & ~63) |
                        (((((tok >> 3) & 7) ^ (dh & 7)) << 3)) | (tok & 7);
                    short4 pk;
                    pk.x = f2bs(a[0]); pk.y = f2bs(a[1]);
                    pk.z = f2bs(a[2]); pk.w = f2bs(a[3]);
                    *(short4*)&vo[((size_t)(b * NH + head) * DH + dh) * SEQ + tokp] = pk;
                } else if (mat == 1) {
                    // K store, dh-granule swizzled by (tok&7)
#pragma unroll
                    for (int rr = 0; rr < 4; ++rr) {
                        const int m = row0 + rr;
                        const int b = m >> 11, tok = m & 2047;
                        const int dhp = (((dh >> 3) ^ (tok & 7)) << 3) | (dh & 7);
                        ko[((size_t)(b * NH + head) * SEQ + tok) * DH + dhp] =
                            f2bs(a[rr]);
                    }
                } else {
#pragma unroll
                    for (int rr = 0; rr < 4; ++rr) {
                        const int m = row0 + rr;
                        const int b = m >> 11, tok = m & 2047;
                        qo[((size_t)(b * NH + head) * SEQ + tok) * DH + dh] =
                            f2bs(a[rr] * QSCALE);
                    }
                }
            } else {
                const float bb = bias[nn];
#pragma unroll
                for (int rr = 0; rr < 4; ++rr) {
                    const float z = a[rr] + bb;
                    outb[(size_t)(row0 + rr) * N + nn] = f2bs(z > 0.f ? z : 0.f);
                }
            }
        }
}

// ---------------------------------------------------------------------------
// 128x128 GEMM, BK=64, double-buffered depth-1, compiler-scheduled
// read+MFMA phase.  4 waves (2x2), per-wave 64x64 over K=64 (16 ds_read :
// 32 MFMA per step) -- halves barrier crossings vs BK=32 (r15: FFN2 at 94us
// = 2.3x the 41us LDS floor; gap is sync overhead + short sched windows).
// LDS 2 x (16K A + 16K B) = 64 KB -> 2 blocks/CU = 8 waves/CU.
// Swizzle (64-short rows): physical 16B-slot p of row r holds linear slot
// p ^ (r & 7); applied on the global source + matching XOR on ds_read ->
// 2-way (free) bank aliasing.
// Ledger: 8 gloads/thread/tile; stage(kt+1) -> VM(8) = tile kt landed.
// EPI: out fp32 = acc + bias[n] + res[m,n]   (proj and FFN2)
// ---------------------------------------------------------------------------
__global__ __launch_bounds__(256) void gemm_bt128(
    const short* __restrict__ A, const short* __restrict__ Bt,
    int N, int K, int nyT,
    const float* __restrict__ bias, const float* __restrict__ res,
    float* __restrict__ outf)
{
    __shared__ short As[2][8192];     // 128 x 64
    __shared__ short Bs[2][8192];
    const int t = threadIdx.x, lane = t & 63, w = t >> 6;
    const int l15 = lane & 15, hi = lane >> 4;
    const int wm = (w & 1) * 64, wn = (w >> 1) * 64;
    int bx, by; swz_xy(nyT, bx, by);
    const int m0 = bx * 128, n0 = by * 128;
    const int NT = K >> 6;

    f32x4 acc[4][4] = {};

    // stage one 128x64 tile (1024 chunks, 4/thread), pre-swizzled source
#define STAGE64(G, row0, k0, lds)                                             \
    do {                                                                      \
        _Pragma("unroll")                                                     \
        for (int i2 = 0; i2 < 4; ++i2) {                                      \
            const int c  = i2 * 256 + t;                                      \
            const int r  = c >> 3;                                            \
            const int sl = (c & 7) ^ (r & 7);                                 \
            gload_lds16(&(G)[(size_t)((row0) + r) * K + (k0) + sl * 8],       \
                        &(lds)[c * 8]);                                       \
        }                                                                     \
    } while (0)

    STAGE64(A, m0, 0, As[0]);
    STAGE64(Bt, n0, 0, Bs[0]);

    for (int kt = 0; kt < NT; ++kt) {
        if (kt + 1 < NT) {
            STAGE64(A,  m0, (kt + 1) << 6, As[(kt + 1) & 1]);
            STAGE64(Bt, n0, (kt + 1) << 6, Bs[(kt + 1) & 1]);
            VM(8);                        // tile kt landed; kt+1 in flight
        } else {
            VM(0);
        }
        __builtin_amdgcn_s_barrier();     // tile kt visible to all waves

        const short* Ac = As[kt & 1];
        const short* Bc = Bs[kt & 1];
        bf16x8 af[4][2], bfr[4][2];
#pragma unroll
        for (int fm = 0; fm < 4; ++fm) {
            const int r = wm + fm * 16 + l15;
#pragma unroll
            for (int ks = 0; ks < 2; ++ks)
                af[fm][ks] = *(const bf16x8*)
                    &Ac[r * 64 + (((ks * 4 + hi) ^ (r & 7)) << 3)];
        }
#pragma unroll
        for (int fn = 0; fn < 4; ++fn) {
            const int r = wn + fn * 16 + l15;
#pragma unroll
            for (int ks = 0; ks < 2; ++ks)
                bfr[fn][ks] = *(const bf16x8*)
                    &Bc[r * 64 + (((ks * 4 + hi) ^ (r & 7)) << 3)];
        }
#pragma unroll
        for (int ks = 0; ks < 2; ++ks)
#pragma unroll
            for (int fm = 0; fm < 4; ++fm)
#pragma unroll
                for (int fn = 0; fn < 4; ++fn)
                    acc[fm][fn] = __builtin_amdgcn_mfma_f32_16x16x32_bf16(
                        af[fm][ks], bfr[fn][ks], acc[fm][fn], 0, 0, 0);

        __builtin_amdgcn_s_barrier();     // all reads of kt done (MFMA deps)
    }
#undef STAGE64

#pragma unroll
    for (int fm = 0; fm < 4; ++fm)
#pragma unroll
        for (int fn = 0; fn < 4; ++fn) {
            const int row0 = m0 + wm + fm * 16 + hi * 4;
            const int nn = n0 + wn + fn * 16 + l15;
            const float bb = bias[nn];
            const f32x4 a = acc[fm][fn];
#pragma unroll
            for (int rr = 0; rr < 4; ++rr) {
                const int m = row0 + rr;
                outf[(size_t)m * N + nn] = a[rr] + bb + res[(size_t)m * N + nn];
            }
        }
}

// ---------------------------------------------------------------------------
// Causal flash attention v6: 8-wave blocks, double-tile staging (one barrier
// per 2 KV tiles).  Unchanged from r15.
// ---------------------------------------------------------------------------
__global__ __launch_bounds__(512) void attn_kernel(
    const short* __restrict__ Q, const short* __restrict__ Kx,
    const short* __restrict__ Vt, short* __restrict__ att)
{
    __shared__ short Ks[2][2][4096];
    __shared__ short Vs[2][2][4096];

    const int n  = blockIdx.x;
    const int bh = n & 63;
    const int j  = n >> 6;                    // 0..7
    const int qb = (j < 4) ? (7 - j) : (j - 4);
    const int tid = threadIdx.x;
    const int lane = tid & 63;
    const int wq = tid >> 6;                  // 0..7
    const int l15 = lane & 15, hi = lane >> 4;
    const int qw = qb * 256 + wq * 32;
    const size_t base  = (size_t)bh * (SEQ * DH);   // Q,K: [bh][tok][dh]
    const size_t vbase = (size_t)bh * (DH * SEQ);   // Vt:  [bh][dh][tok]
    const int b = bh >> 4, head = bh & 15;

    // Q fragments (B-operand): [q=l15][k=hi*8..+7]
    bf16x8 qf[2][2];
#pragma unroll
    for (int mf = 0; mf < 2; ++mf)
#pragma unroll
        for (int kf = 0; kf < 2; ++kf)
            qf[mf][kf] = *(const bf16x8*)
                &Q[base + (size_t)(qw + mf * 16 + l15) * DH + kf * 32 + hi * 8];

    f32x4 O[2][4] = {};
    float L[2] = {0.f, 0.f};

    const int nkv_blk = 4 * qb + 4;           // tiles staged by the block
    const int ndt     = nkv_blk >> 1;         // double-tiles
    const int nkv_wv  = (qw + 95) >> 6;       // tiles this wave computes

    // ---- stage a DOUBLE tile (128 kv rows): 4 loads/thread ----
#define STAGE_KV2(DT, BUF)                                                     \
    do {                                                                       \
        const int kvo = (DT) * 128;                                            \
        const int rw = tid >> 3, sl = tid & 7;                                 \
        _Pragma("unroll")                                                      \
        for (int sb = 0; sb < 2; ++sb) {                                       \
            gload_lds16(&Kx[base + (size_t)(kvo + sb * 64 + rw) * DH + sl * 8],\
                        &Ks[BUF][sb][tid * 8]);                                \
            gload_lds16(&Vt[vbase + (size_t)rw * SEQ + kvo + sb * 64 + sl * 8],\
                        &Vs[BUF][sb][tid * 8]);                                \
        }                                                                      \
    } while (0)

    STAGE_KV2(0, 0);

    for (int dt = 0; dt < ndt; ++dt) {
        VM(0);                               // this wave's staged loads landed
        __builtin_amdgcn_s_barrier();        // all waves' loads landed
        if (dt + 1 < ndt) STAGE_KV2(dt + 1, (dt + 1) & 1);

#pragma unroll
        for (int sb = 0; sb < 2; ++sb) {
            const int t2 = dt * 2 + sb;
            if (t2 >= nkv_wv) break;
            const short* Kc = &Ks[dt & 1][sb][0];
            const short* Vc = &Vs[dt & 1][sb][0];
            const int kv0 = t2 * 64;

            // K fragments (A-operand): row = kv-local, swizzled read
            bf16x8 kfr[4][2];
#pragma unroll
            for (int nf = 0; nf < 4; ++nf)
#pragma unroll
                for (int kf = 0; kf < 2; ++kf)
                    kfr[nf][kf] = *(const bf16x8*)
                        &Kc[(nf * 16 + l15) * 64 + (((kf * 4 + hi) ^ (l15 & 7)) << 3)];

            // St[kv][q] = K . Q^T  (swapped)
            f32x4 St[4][2] = {};
#pragma unroll
            for (int kf = 0; kf < 2; ++kf)
#pragma unroll
                for (int nf = 0; nf < 4; ++nf)
#pragma unroll
                    for (int mf = 0; mf < 2; ++mf)
                        St[nf][mf] = __builtin_amdgcn_mfma_f32_16x16x32_bf16(
                            kfr[nf][kf], qf[mf][kf], St[nf][mf], 0, 0, 0);

            if (kv0 + 63 > qw) {   // causal tail masking
#pragma unroll
                for (int mf = 0; mf < 2; ++mf) {
                    const int q = qw + mf * 16 + l15;
#pragma unroll
                    for (int nf = 0; nf < 4; ++nf)
#pragma unroll
                        for (int r = 0; r < 4; ++r) {
                            const int kv = kv0 + nf * 16 + hi * 4 + r;
                            if (kv > q) St[nf][mf][r] = -3.0e38f;
                        }
                }
            }

            // P = exp2(St); per-tile partial L; pack to bf16 A-frags in regs
            float lp[2] = {0.f, 0.f};
            s16x4 pa[4][2];
#pragma unroll
            for (int nf = 0; nf < 4; ++nf)
#pragma unroll
                for (int mf = 0; mf < 2; ++mf) {
                    const float p0 = exp2f(St[nf][mf][0]);
                    const float p1 = exp2f(St[nf][mf][1]);
                    const float p2 = exp2f(St[nf][mf][2]);
                    const float p3 = exp2f(St[nf][mf][3]);
                    lp[mf] += (p0 + p1) + (p2 + p3);
                    unsigned dw0, dw1;
                    asm("v_cvt_pk_bf16_f32 %0, %1, %2" : "=v"(dw0) : "v"(p0), "v"(p1));
                    asm("v_cvt_pk_bf16_f32 %0, %1, %2" : "=v"(dw1) : "v"(p2), "v"(p3));
                    i32x2 dd; dd[0] = (int)dw0; dd[1] = (int)dw1;
                    pa[nf][mf] = __builtin_bit_cast(s16x4, dd);
                }
            L[0] += lp[0]; L[1] += lp[1];

            // PV: O[q][d] += P . V  (16x16x16, A = pa regs, B = V^T in LDS)
#pragma unroll
            for (int nf = 0; nf < 4; ++nf)
#pragma unroll
                for (int jf = 0; jf < 4; ++jf) {
                    const s16x4 vfr = *(const s16x4*)
                        &Vc[(jf * 16 + l15) * 64 +
                            ((((nf * 2 + (hi >> 1)) ^ (l15 & 7)) << 3) + ((hi & 1) << 2))];
#pragma unroll
                    for (int mf = 0; mf < 2; ++mf)
                        O[mf][jf] = __builtin_amdgcn_mfma_f32_16x16x16bf16_1k(
                            pa[nf][mf], vfr, O[mf][jf], 0, 0, 0);
                }
        }
    }
#undef STAGE_KV2

    // L: reduce across hi groups (lane holds L for q = qw + mf*16 + l15)
#pragma unroll
    for (int mf = 0; mf < 2; ++mf) {
        L[mf] += __shfl_xor(L[mf], 16, 64);
        L[mf] += __shfl_xor(L[mf], 32, 64);
    }
    const float inv0 = 1.0f / L[0], inv1 = 1.0f / L[1];

    // redistribute 1/L from col-space (l15=q) to row-space (hi*4+r=q)
#pragma unroll
    for (int mf = 0; mf < 2; ++mf) {
        const float invm = mf ? inv1 : inv0;
#pragma unroll
        for (int r = 0; r < 4; ++r) {
            const int addr = ((lane >> 4) << 4) + (r << 2);   // 4*(hi*4+r)
            const float iv = __builtin_bit_cast(float,
                __builtin_amdgcn_ds_bpermute(addr, __builtin_bit_cast(int, invm)));
            const int q = qw + mf * 16 + hi * 4 + r;
#pragma unroll
            for (int jf = 0; jf < 4; ++jf)
                att[(size_t)(b * SEQ + q) * DM + head * DH + jf * 16 + l15] =
                    f2bs(O[mf][jf][r] * iv);
        }
    }
}

// ---------------------------------------------------------------------------
extern "C" void kernel_launch(void* const* d_in, const int* in_sizes, int n_in,
                              void* d_out, int out_size, void* d_ws, size_t ws_size,
                              hipStream_t stream) {
    const float* x   = (const float*)d_in[0];
    const float* wq  = (const float*)d_in[1];
    const float* wk  = (const float*)d_in[2];
    const float* wv  = (const float*)d_in[3];
    const float* wp  = (const float*)d_in[4];
    const float* bp  = (const float*)d_in[5];
    const float* w1  = (const float*)d_in[6];
    const float* b1  = (const float*)d_in[7];
    const float* w2  = (const float*)d_in[8];
    const float* b2  = (const float*)d_in[9];
    const float* g1  = (const float*)d_in[10];
    const float* be1 = (const float*)d_in[11];
    const float* g2  = (const float*)d_in[12];
    const float* be2 = (const float*)d_in[13];
    float* out = (float*)d_out;

    char* ws = (char*)d_ws;
    short* wqkv_t = (short*)(ws + 0);          //  6.0 MB  [3072][1024]
    short* wp_t   = (short*)(ws + 6291456);    //  2.0 MB  [1024][1024]
    short* w1_t   = (short*)(ws + 8388608);    //  8.0 MB  [4096][1024]
    short* w2_t   = (short*)(ws + 16777216);   //  8.0 MB  [1024][4096]
    short* h      = (short*)(ws + 25165824);   // 16 MB
    short* qb     = (short*)(ws + 41943040);   // 16 MB
    short* kb     = (short*)(ws + 58720256);   // 16 MB
    short* vb     = (short*)(ws + 75497472);   // 16 MB
    short* att    = (short*)(ws + 92274688);   // 16 MB
    float* x1     = (float*)(ws + 109051904);  // 32 MB
    short* h2     = (short*)(ws + 142606336);  // 16 MB
    short* tbuf   = (short*)(ws + 25165824);   // 64 MB, aliases h/qb/kb/vb (dead)

    dim3 blk(256);

    transpose_cvt_kernel<<<dim3(16, 16), blk, 0, stream>>>(wq, wqkv_t,                1024, 1024);
    transpose_cvt_kernel<<<dim3(16, 16), blk, 0, stream>>>(wk, wqkv_t + 1024 * 1024,  1024, 1024);
    transpose_cvt_kernel<<<dim3(16, 16), blk, 0, stream>>>(wv, wqkv_t + 2048 * 1024,  1024, 1024);
    transpose_cvt_kernel<<<dim3(16, 16), blk, 0, stream>>>(wp, wp_t,                  1024, 1024);
    transpose_cvt_kernel<<<dim3(16, 64), blk, 0, stream>>>(w1, w1_t,                  1024, 4096);
    transpose_cvt_kernel<<<dim3(64, 16), blk, 0, stream>>>(w2, w2_t,                  4096, 1024);

    ln_kernel<<<MROWS, blk, 0, stream>>>(x, g1, be1, h);

    gemm256<0><<<dim3(384), dim3(512), 0, stream>>>(h, wqkv_t, 3072, 1024, 12,
        nullptr, nullptr, qb, kb, vb);

    attn_kernel<<<dim3(512), dim3(512), 0, stream>>>(qb, kb, vb, att);

    gemm_bt128<<<dim3(512), blk, 0, stream>>>(att, wp_t, 1024, 1024, 8,
        bp, x, x1);

    ln_kernel<<<MROWS, blk, 0, stream>>>(x1, g2, be2, h2);

    gemm256<2><<<dim3(512), dim3(512), 0, stream>>>(h2, w1_t, 4096, 1024, 16,
        b1, tbuf, nullptr, nullptr, nullptr);

    gemm_bt128<<<dim3(512), blk, 0, stream>>>(tbuf, w2_t, 1024, 4096, 8,
        b2, x1, out);
}

// Round 18
// 364.557 us; speedup vs baseline: 1.1818x; 1.0083x over previous
//
#include <hip/hip_runtime.h>
#include <hip/hip_bf16.h>
#include <stdint.h>

// Problem constants
#define DM   1024
#define NH   16
#define DH   64
#define BATCH 4
#define SEQ  2048
#define MROWS (BATCH*SEQ)   // 8192

typedef float f32x4 __attribute__((ext_vector_type(4)));
typedef __bf16 bf16x8 __attribute__((ext_vector_type(8)));
typedef short s16x4 __attribute__((ext_vector_type(4)));
typedef int   i32x2 __attribute__((ext_vector_type(2)));

// Q is pre-scaled by (1/sqrt(D)) * log2(e) so softmax can use exp2 directly.
#define QSCALE 0.045084220f

#define VM(n) asm volatile("s_waitcnt vmcnt(" #n ")" ::: "memory")
#define LGKM0 do { asm volatile("s_waitcnt lgkmcnt(0)" ::: "memory"); \
                   __builtin_amdgcn_sched_barrier(0); } while (0)

__device__ __forceinline__ short f2bs(float f) {
    __bf16 h = (__bf16)f;
    return __builtin_bit_cast(short, h);
}

__device__ __forceinline__ void gload_lds16(const void* g, void* l) {
    __builtin_amdgcn_global_load_lds(
        (__attribute__((address_space(1))) void*)(g),
        (__attribute__((address_space(3))) void*)(l), 16, 0, 0);
}

// XCD-chunked bijective swizzle (grid % 8 == 0), n-tile fastest within chunk.
__device__ __forceinline__ void swz_xy(int ny, int& x, int& y) {
    const int bid = blockIdx.x;
    const int cpx = gridDim.x >> 3;
    const int wg  = (bid & 7) * cpx + (bid >> 3);
    x = wg / ny;
    y = wg % ny;
}

// ---------------------------------------------------------------------------
// Transpose + fp32->bf16 convert: wt[n][k] = bf16(w[k][n]).  64x64 tiles.
// ---------------------------------------------------------------------------
__global__ __launch_bounds__(256) void transpose_cvt_kernel(
    const float* __restrict__ w, short* __restrict__ wt, int K, int N)
{
    __shared__ short tile[64 * 65];
    const int k0 = blockIdx.x * 64, n0 = blockIdx.y * 64;
    const int t = threadIdx.x;
#pragma unroll
    for (int i = 0; i < 16; ++i) {
        int idx = i * 256 + t;
        int r = idx >> 6, c = idx & 63;
        tile[r * 65 + c] = f2bs(w[(size_t)(k0 + r) * N + n0 + c]);
    }
    __syncthreads();
#pragma unroll
    for (int i = 0; i < 16; ++i) {
        int idx = i * 256 + t;
        int r = idx >> 6, c = idx & 63;      // r: n-local, c: k-local
        wt[(size_t)(n0 + r) * K + k0 + c] = tile[c * 65 + r];
    }
}

// ---------------------------------------------------------------------------
// LayerNorm (rows of 1024 fp32) -> bf16
// ---------------------------------------------------------------------------
__global__ __launch_bounds__(256) void ln_kernel(
    const float* __restrict__ x, const float* __restrict__ g,
    const float* __restrict__ be, short* __restrict__ out)
{
    const int row = blockIdx.x, t = threadIdx.x;
    const float4 v = ((const float4*)(x + (size_t)row * DM))[t];
    float s  = v.x + v.y + v.z + v.w;
    float ss = v.x * v.x + v.y * v.y + v.z * v.z + v.w * v.w;
#pragma unroll
    for (int d = 1; d < 64; d <<= 1) {
        s  += __shfl_xor(s, d, 64);
        ss += __shfl_xor(ss, d, 64);
    }
    __shared__ float red[8];
    const int wid = t >> 6;
    if ((t & 63) == 0) { red[wid] = s; red[wid + 4] = ss; }
    __syncthreads();
    s  = red[0] + red[1] + red[2] + red[3];
    ss = red[4] + red[5] + red[6] + red[7];
    const float mu = s * (1.0f / DM);
    const float rs = rsqrtf(ss * (1.0f / DM) - mu * mu + 1e-5f);
    const float4 gg = ((const float4*)g)[t];
    const float4 bb = ((const float4*)be)[t];
    short4 o;
    o.x = f2bs((v.x - mu) * rs * gg.x + bb.x);
    o.y = f2bs((v.y - mu) * rs * gg.y + bb.y);
    o.z = f2bs((v.z - mu) * rs * gg.z + bb.z);
    o.w = f2bs((v.w - mu) * rs * gg.w + bb.w);
    ((short4*)(out + (size_t)row * DM))[t] = o;
}

// ---------------------------------------------------------------------------
// Staging: rows x 32-short K-slab (512-thread GEMMs).  LDS linear; global
// source pre-swizzled (slot s holds linear slot s ^ ((row>>1)&3)).
// ---------------------------------------------------------------------------
template<int NCHUNK>   // 16B chunks per tile: rows*4
__device__ __forceinline__ void stage32(
    const short* __restrict__ G, int ldk, int row0, int k0,
    short* __restrict__ lds, int t)
{
#pragma unroll
    for (int i = 0; i < NCHUNK / 512; ++i) {
        const int c  = i * 512 + t;
        const int r  = c >> 2;
        const int sl = (c & 3) ^ ((r >> 1) & 3);
        gload_lds16(&G[(size_t)(row0 + r) * ldk + k0 + sl * 8], &lds[c * 8]);
    }
}

// ---------------------------------------------------------------------------
// 256x256 GEMM, BK=32, 4-buffer depth-3 prefetch, TWO 16-MFMA phases per
// K-step, counted vmcnt at phase B only.  8 waves (2M x 4N).
// EPI 0: QKV scatter (K and V^T stored PRE-SWIZZLED for attn LDS staging).
// EPI 2: relu(acc+bias) -> bf16.
// ---------------------------------------------------------------------------
template<int EPI>
__global__ __launch_bounds__(512) void gemm256(
    const short* __restrict__ A, const short* __restrict__ Bt,
    int N, int K, int nyT,
    const float* __restrict__ bias, short* __restrict__ outb,
    short* __restrict__ qo, short* __restrict__ ko, short* __restrict__ vo)
{
    __shared__ short As[4][8192];
    __shared__ short Bs[4][8192];
    const int t = threadIdx.x, lane = t & 63, w = t >> 6;
    const int l15 = lane & 15, hi = lane >> 4;
    const int wm = (w >> 2) * 128, wn = (w & 3) * 64;
    int bx, by; swz_xy(nyT, bx, by);
    const int m0 = bx * 256, n0 = by * 256;
    const int NT = K >> 5;

    f32x4 acc[8][4] = {};

    stage32<1024>(A, K, m0, 0,  As[0], t); stage32<1024>(Bt, K, n0, 0,  Bs[0], t);
    stage32<1024>(A, K, m0, 32, As[1], t); stage32<1024>(Bt, K, n0, 32, Bs[1], t);
    stage32<1024>(A, K, m0, 64, As[2], t); stage32<1024>(Bt, K, n0, 64, Bs[2], t);
    VM(8);                              // tile 0 (A,B) landed
    __builtin_amdgcn_s_barrier();

    for (int kt = 0; kt < NT; ++kt) {
        const short* Ac = As[kt & 3];
        const short* Bc = Bs[kt & 3];
        const int k3 = (kt + 3) << 5;
        bf16x8 af[8], bfr[4];

        // ---- phase A: fm 0..3 ; stage A(kt+3) ----
#pragma unroll
        for (int fm = 0; fm < 4; ++fm) {
            const int r = wm + fm * 16 + l15;
            af[fm] = *(const bf16x8*)&Ac[r * 32 + ((hi ^ ((r >> 1) & 3)) << 3)];
        }
#pragma unroll
        for (int fn = 0; fn < 4; ++fn) {
            const int r = wn + fn * 16 + l15;
            bfr[fn] = *(const bf16x8*)&Bc[r * 32 + ((hi ^ ((r >> 1) & 3)) << 3)];
        }
        if (kt + 3 < NT) stage32<1024>(A, K, m0, k3, As[(kt + 3) & 3], t);
        __builtin_amdgcn_s_barrier();
        LGKM0;
        __builtin_amdgcn_s_setprio(1);
#pragma unroll
        for (int fm = 0; fm < 4; ++fm)
#pragma unroll
            for (int fn = 0; fn < 4; ++fn)
                acc[fm][fn] = __builtin_amdgcn_mfma_f32_16x16x32_bf16(
                    af[fm], bfr[fn], acc[fm][fn], 0, 0, 0);
        __builtin_amdgcn_s_setprio(0);
        __builtin_amdgcn_s_barrier();

        // ---- phase B: fm 4..7 ; stage B(kt+3) ; counted vmcnt ----
#pragma unroll
        for (int fm = 4; fm < 8; ++fm) {
            const int r = wm + fm * 16 + l15;
            af[fm] = *(const bf16x8*)&Ac[r * 32 + ((hi ^ ((r >> 1) & 3)) << 3)];
        }
        if (kt + 3 < NT) {
            stage32<1024>(Bt, K, n0, k3, Bs[(kt + 3) & 3], t);
            VM(8);
        } else if (kt + 2 < NT) VM(4);
        else if (kt + 1 < NT) VM(0);
        __builtin_amdgcn_s_barrier();
        LGKM0;
        __builtin_amdgcn_s_setprio(1);
#pragma unroll
        for (int fm = 4; fm < 8; ++fm)
#pragma unroll
            for (int fn = 0; fn < 4; ++fn)
                acc[fm][fn] = __builtin_amdgcn_mfma_f32_16x16x32_bf16(
                    af[fm], bfr[fn], acc[fm][fn], 0, 0, 0);
        __builtin_amdgcn_s_setprio(0);
        __builtin_amdgcn_s_barrier();
    }

#pragma unroll
    for (int fm = 0; fm < 8; ++fm)
#pragma unroll
        for (int fn = 0; fn < 4; ++fn) {
            const int row0 = m0 + wm + fm * 16 + hi * 4;
            const int nn = n0 + wn + fn * 16 + l15;
            const f32x4 a = acc[fm][fn];
            if constexpr (EPI == 0) {
                const int mat = nn >> 10, n1 = nn & 1023;
                const int head = n1 >> 6, dh = n1 & 63;
                if (mat == 2) {
                    // V^T store, tok-granule swizzled by (dh&7)
                    const int tok = row0 & 2047, b = row0 >> 11;
                    const int tokp = (tok & ~63) |
                        (((((tok >> 3) & 7) ^ (dh & 7)) << 3)) | (tok & 7);
                    short4 pk;
                    pk.x = f2bs(a[0]); pk.y = f2bs(a[1]);
                    pk.z = f2bs(a[2]); pk.w = f2bs(a[3]);
                    *(short4*)&vo[((size_t)(b * NH + head) * DH + dh) * SEQ + tokp] = pk;
                } else if (mat == 1) {
                    // K store, dh-granule swizzled by (tok&7)
#pragma unroll
                    for (int rr = 0; rr < 4; ++rr) {
                        const int m = row0 + rr;
                        const int b = m >> 11, tok = m & 2047;
                        const int dhp = (((dh >> 3) ^ (tok & 7)) << 3) | (dh & 7);
                        ko[((size_t)(b * NH + head) * SEQ + tok) * DH + dhp] =
                            f2bs(a[rr]);
                    }
                } else {
#pragma unroll
                    for (int rr = 0; rr < 4; ++rr) {
                        const int m = row0 + rr;
                        const int b = m >> 11, tok = m & 2047;
                        qo[((size_t)(b * NH + head) * SEQ + tok) * DH + dh] =
                            f2bs(a[rr] * QSCALE);
                    }
                }
            } else {
                const float bb = bias[nn];
#pragma unroll
                for (int rr = 0; rr < 4; ++rr) {
                    const float z = a[rr] + bb;
                    outb[(size_t)(row0 + rr) * N + nn] = f2bs(z > 0.f ? z : 0.f);
                }
            }
        }
}

// ---------------------------------------------------------------------------
// 128x128 GEMM, BK=64, double-buffered depth-1, compiler-scheduled
// read+MFMA phase.  4 waves (2x2), per-wave 64x64 over K=64.
// LDS 2 x (16K A + 16K B) = 64 KB -> 2 blocks/CU = 8 waves/CU.
// EPI: out fp32 = acc + bias[n] + res[m,n]   (proj and FFN2)
// ---------------------------------------------------------------------------
__global__ __launch_bounds__(256) void gemm_bt128(
    const short* __restrict__ A, const short* __restrict__ Bt,
    int N, int K, int nyT,
    const float* __restrict__ bias, const float* __restrict__ res,
    float* __restrict__ outf)
{
    __shared__ short As[2][8192];     // 128 x 64
    __shared__ short Bs[2][8192];
    const int t = threadIdx.x, lane = t & 63, w = t >> 6;
    const int l15 = lane & 15, hi = lane >> 4;
    const int wm = (w & 1) * 64, wn = (w >> 1) * 64;
    int bx, by; swz_xy(nyT, bx, by);
    const int m0 = bx * 128, n0 = by * 128;
    const int NT = K >> 6;

    f32x4 acc[4][4] = {};

    // stage one 128x64 tile (1024 chunks, 4/thread), pre-swizzled source
#define STAGE64(G, row0, k0, lds)                                             \
    do {                                                                      \
        _Pragma("unroll")                                                     \
        for (int i2 = 0; i2 < 4; ++i2) {                                      \
            const int c  = i2 * 256 + t;                                      \
            const int r  = c >> 3;                                            \
            const int sl = (c & 7) ^ (r & 7);                                 \
            gload_lds16(&(G)[(size_t)((row0) + r) * K + (k0) + sl * 8],       \
                        &(lds)[c * 8]);                                       \
        }                                                                     \
    } while (0)

    STAGE64(A, m0, 0, As[0]);
    STAGE64(Bt, n0, 0, Bs[0]);

    for (int kt = 0; kt < NT; ++kt) {
        if (kt + 1 < NT) {
            STAGE64(A,  m0, (kt + 1) << 6, As[(kt + 1) & 1]);
            STAGE64(Bt, n0, (kt + 1) << 6, Bs[(kt + 1) & 1]);
            VM(8);                        // tile kt landed; kt+1 in flight
        } else {
            VM(0);
        }
        __builtin_amdgcn_s_barrier();     // tile kt visible to all waves

        const short* Ac = As[kt & 1];
        const short* Bc = Bs[kt & 1];
        bf16x8 af[4][2], bfr[4][2];
#pragma unroll
        for (int fm = 0; fm < 4; ++fm) {
            const int r = wm + fm * 16 + l15;
#pragma unroll
            for (int ks = 0; ks < 2; ++ks)
                af[fm][ks] = *(const bf16x8*)
                    &Ac[r * 64 + (((ks * 4 + hi) ^ (r & 7)) << 3)];
        }
#pragma unroll
        for (int fn = 0; fn < 4; ++fn) {
            const int r = wn + fn * 16 + l15;
#pragma unroll
            for (int ks = 0; ks < 2; ++ks)
                bfr[fn][ks] = *(const bf16x8*)
                    &Bc[r * 64 + (((ks * 4 + hi) ^ (r & 7)) << 3)];
        }
#pragma unroll
        for (int ks = 0; ks < 2; ++ks)
#pragma unroll
            for (int fm = 0; fm < 4; ++fm)
#pragma unroll
                for (int fn = 0; fn < 4; ++fn)
                    acc[fm][fn] = __builtin_amdgcn_mfma_f32_16x16x32_bf16(
                        af[fm][ks], bfr[fn][ks], acc[fm][fn], 0, 0, 0);

        __builtin_amdgcn_s_barrier();     // all reads of kt done (MFMA deps)
    }
#undef STAGE64

#pragma unroll
    for (int fm = 0; fm < 4; ++fm)
#pragma unroll
        for (int fn = 0; fn < 4; ++fn) {
            const int row0 = m0 + wm + fm * 16 + hi * 4;
            const int nn = n0 + wn + fn * 16 + l15;
            const float bb = bias[nn];
            const f32x4 a = acc[fm][fn];
#pragma unroll
            for (int rr = 0; rr < 4; ++rr) {
                const int m = row0 + rr;
                outf[(size_t)m * N + nn] = a[rr] + bb + res[(size_t)m * N + nn];
            }
        }
}

// ---------------------------------------------------------------------------
// Causal flash attention v7: 8-wave blocks, IN-BLOCK HEAVY/LIGHT PAIRING.
// Block = (bh, p in 0..7): waves 0-3 own q-chunk p*128, waves 4-7 own chunk
// (15-p)*128 -> every block does a constant 34 KV-tiles, all blocks live
// equally long, 16 waves/CU resident throughout (r17: light blocks died
// early -> 8 waves/CU for 95% of the kernel, occupancy 17%).
// K/V staged once per block for the heavy chunk's range; light waves stop
// computing early (t2 >= nkv_wv) but keep hitting barriers.
// Double-tile staging, one barrier per 2 KV tiles (r15 schedule, unchanged).
// ---------------------------------------------------------------------------
__global__ __launch_bounds__(512) void attn_kernel(
    const short* __restrict__ Q, const short* __restrict__ Kx,
    const short* __restrict__ Vt, short* __restrict__ att)
{
    __shared__ short Ks[2][2][4096];
    __shared__ short Vs[2][2][4096];

    const int n  = blockIdx.x;
    const int bh = n & 63;
    const int p  = n >> 6;                    // 0..7
    const int tid = threadIdx.x;
    const int lane = tid & 63;
    const int wq = tid >> 6;                  // 0..7
    const int l15 = lane & 15, hi = lane >> 4;
    // waves 0-3: chunk p (rows p*128 + wq*32); waves 4-7: chunk 15-p
    const int qw = (wq < 4) ? (p * 128 + wq * 32)
                            : ((15 - p) * 128 + (wq - 4) * 32);
    const size_t base  = (size_t)bh * (SEQ * DH);   // Q,K: [bh][tok][dh]
    const size_t vbase = (size_t)bh * (DH * SEQ);   // Vt:  [bh][dh][tok]
    const int b = bh >> 4, head = bh & 15;

    // Q fragments (B-operand): [q=l15][k=hi*8..+7]
    bf16x8 qf[2][2];
#pragma unroll
    for (int mf = 0; mf < 2; ++mf)
#pragma unroll
        for (int kf = 0; kf < 2; ++kf)
            qf[mf][kf] = *(const bf16x8*)
                &Q[base + (size_t)(qw + mf * 16 + l15) * DH + kf * 32 + hi * 8];

    f32x4 O[2][4] = {};
    float L[2] = {0.f, 0.f};

    const int ndt    = 16 - p;                // double-tiles staged (heavy chunk)
    const int nkv_wv = (qw + 95) >> 6;        // tiles this wave computes

    // ---- stage a DOUBLE tile (128 kv rows): 4 loads/thread ----
#define STAGE_KV2(DT, BUF)                                                     \
    do {                                                                       \
        const int kvo = (DT) * 128;                                            \
        const int rw = tid >> 3, sl = tid & 7;                                 \
        _Pragma("unroll")                                                      \
        for (int sb = 0; sb < 2; ++sb) {                                       \
            gload_lds16(&Kx[base + (size_t)(kvo + sb * 64 + rw) * DH + sl * 8],\
                        &Ks[BUF][sb][tid * 8]);                                \
            gload_lds16(&Vt[vbase + (size_t)rw * SEQ + kvo + sb * 64 + sl * 8],\
                        &Vs[BUF][sb][tid * 8]);                                \
        }                                                                      \
    } while (0)

    STAGE_KV2(0, 0);

    for (int dt = 0; dt < ndt; ++dt) {
        VM(0);                               // this wave's staged loads landed
        __builtin_amdgcn_s_barrier();        // all waves' loads landed
        if (dt + 1 < ndt) STAGE_KV2(dt + 1, (dt + 1) & 1);

#pragma unroll
        for (int sb = 0; sb < 2; ++sb) {
            const int t2 = dt * 2 + sb;
            if (t2 >= nkv_wv) break;
            const short* Kc = &Ks[dt & 1][sb][0];
            const short* Vc = &Vs[dt & 1][sb][0];
            const int kv0 = t2 * 64;

            // K fragments (A-operand): row = kv-local, swizzled read
            bf16x8 kfr[4][2];
#pragma unroll
            for (int nf = 0; nf < 4; ++nf)
#pragma unroll
                for (int kf = 0; kf < 2; ++kf)
                    kfr[nf][kf] = *(const bf16x8*)
                        &Kc[(nf * 16 + l15) * 64 + (((kf * 4 + hi) ^ (l15 & 7)) << 3)];

            // St[kv][q] = K . Q^T  (swapped)
            f32x4 St[4][2] = {};
#pragma unroll
            for (int kf = 0; kf < 2; ++kf)
#pragma unroll
                for (int nf = 0; nf < 4; ++nf)
#pragma unroll
                    for (int mf = 0; mf < 2; ++mf)
                        St[nf][mf] = __builtin_amdgcn_mfma_f32_16x16x32_bf16(
                            kfr[nf][kf], qf[mf][kf], St[nf][mf], 0, 0, 0);

            if (kv0 + 63 > qw) {   // causal tail masking
#pragma unroll
                for (int mf = 0; mf < 2; ++mf) {
                    const int q = qw + mf * 16 + l15;
#pragma unroll
                    for (int nf = 0; nf < 4; ++nf)
#pragma unroll
                        for (int r = 0; r < 4; ++r) {
                            const int kv = kv0 + nf * 16 + hi * 4 + r;
                            if (kv > q) St[nf][mf][r] = -3.0e38f;
                        }
                }
            }

            // P = exp2(St); per-tile partial L; pack to bf16 A-frags in regs
            float lp[2] = {0.f, 0.f};
            s16x4 pa[4][2];
#pragma unroll
            for (int nf = 0; nf < 4; ++nf)
#pragma unroll
                for (int mf = 0; mf < 2; ++mf) {
                    const float p0 = exp2f(St[nf][mf][0]);
                    const float p1 = exp2f(St[nf][mf][1]);
                    const float p2 = exp2f(St[nf][mf][2]);
                    const float p3 = exp2f(St[nf][mf][3]);
                    lp[mf] += (p0 + p1) + (p2 + p3);
                    unsigned dw0, dw1;
                    asm("v_cvt_pk_bf16_f32 %0, %1, %2" : "=v"(dw0) : "v"(p0), "v"(p1));
                    asm("v_cvt_pk_bf16_f32 %0, %1, %2" : "=v"(dw1) : "v"(p2), "v"(p3));
                    i32x2 dd; dd[0] = (int)dw0; dd[1] = (int)dw1;
                    pa[nf][mf] = __builtin_bit_cast(s16x4, dd);
                }
            L[0] += lp[0]; L[1] += lp[1];

            // PV: O[q][d] += P . V  (16x16x16, A = pa regs, B = V^T in LDS)
#pragma unroll
            for (int nf = 0; nf < 4; ++nf)
#pragma unroll
                for (int jf = 0; jf < 4; ++jf) {
                    const s16x4 vfr = *(const s16x4*)
                        &Vc[(jf * 16 + l15) * 64 +
                            ((((nf * 2 + (hi >> 1)) ^ (l15 & 7)) << 3) + ((hi & 1) << 2))];
#pragma unroll
                    for (int mf = 0; mf < 2; ++mf)
                        O[mf][jf] = __builtin_amdgcn_mfma_f32_16x16x16bf16_1k(
                            pa[nf][mf], vfr, O[mf][jf], 0, 0, 0);
                }
        }
    }
#undef STAGE_KV2

    // L: reduce across hi groups (lane holds L for q = qw + mf*16 + l15)
#pragma unroll
    for (int mf = 0; mf < 2; ++mf) {
        L[mf] += __shfl_xor(L[mf], 16, 64);
        L[mf] += __shfl_xor(L[mf], 32, 64);
    }
    const float inv0 = 1.0f / L[0], inv1 = 1.0f / L[1];

    // redistribute 1/L from col-space (l15=q) to row-space (hi*4+r=q)
#pragma unroll
    for (int mf = 0; mf < 2; ++mf) {
        const float invm = mf ? inv1 : inv0;
#pragma unroll
        for (int r = 0; r < 4; ++r) {
            const int addr = ((lane >> 4) << 4) + (r << 2);   // 4*(hi*4+r)
            const float iv = __builtin_bit_cast(float,
                __builtin_amdgcn_ds_bpermute(addr, __builtin_bit_cast(int, invm)));
            const int q = qw + mf * 16 + hi * 4 + r;
#pragma unroll
            for (int jf = 0; jf < 4; ++jf)
                att[(size_t)(b * SEQ + q) * DM + head * DH + jf * 16 + l15] =
                    f2bs(O[mf][jf][r] * iv);
        }
    }
}

// ---------------------------------------------------------------------------
extern "C" void kernel_launch(void* const* d_in, const int* in_sizes, int n_in,
                              void* d_out, int out_size, void* d_ws, size_t ws_size,
                              hipStream_t stream) {
    const float* x   = (const float*)d_in[0];
    const float* wq  = (const float*)d_in[1];
    const float* wk  = (const float*)d_in[2];
    const float* wv  = (const float*)d_in[3];
    const float* wp  = (const float*)d_in[4];
    const float* bp  = (const float*)d_in[5];
    const float* w1  = (const float*)d_in[6];
    const float* b1  = (const float*)d_in[7];
    const float* w2  = (const float*)d_in[8];
    const float* b2  = (const float*)d_in[9];
    const float* g1  = (const float*)d_in[10];
    const float* be1 = (const float*)d_in[11];
    const float* g2  = (const float*)d_in[12];
    const float* be2 = (const float*)d_in[13];
    float* out = (float*)d_out;

    char* ws = (char*)d_ws;
    short* wqkv_t = (short*)(ws + 0);          //  6.0 MB  [3072][1024]
    short* wp_t   = (short*)(ws + 6291456);    //  2.0 MB  [1024][1024]
    short* w1_t   = (short*)(ws + 8388608);    //  8.0 MB  [4096][1024]
    short* w2_t   = (short*)(ws + 16777216);   //  8.0 MB  [1024][4096]
    short* h      = (short*)(ws + 25165824);   // 16 MB
    short* qb     = (short*)(ws + 41943040);   // 16 MB
    short* kb     = (short*)(ws + 58720256);   // 16 MB
    short* vb     = (short*)(ws + 75497472);   // 16 MB
    short* att    = (short*)(ws + 92274688);   // 16 MB
    float* x1     = (float*)(ws + 109051904);  // 32 MB
    short* h2     = (short*)(ws + 142606336);  // 16 MB
    short* tbuf   = (short*)(ws + 25165824);   // 64 MB, aliases h/qb/kb/vb (dead)

    dim3 blk(256);

    transpose_cvt_kernel<<<dim3(16, 16), blk, 0, stream>>>(wq, wqkv_t,                1024, 1024);
    transpose_cvt_kernel<<<dim3(16, 16), blk, 0, stream>>>(wk, wqkv_t + 1024 * 1024,  1024, 1024);
    transpose_cvt_kernel<<<dim3(16, 16), blk, 0, stream>>>(wv, wqkv_t + 2048 * 1024,  1024, 1024);
    transpose_cvt_kernel<<<dim3(16, 16), blk, 0, stream>>>(wp, wp_t,                  1024, 1024);
    transpose_cvt_kernel<<<dim3(16, 64), blk, 0, stream>>>(w1, w1_t,                  1024, 4096);
    transpose_cvt_kernel<<<dim3(64, 16), blk, 0, stream>>>(w2, w2_t,                  4096, 1024);

    ln_kernel<<<MROWS, blk, 0, stream>>>(x, g1, be1, h);

    gemm256<0><<<dim3(384), dim3(512), 0, stream>>>(h, wqkv_t, 3072, 1024, 12,
        nullptr, nullptr, qb, kb, vb);

    attn_kernel<<<dim3(512), dim3(512), 0, stream>>>(qb, kb, vb, att);

    gemm_bt128<<<dim3(512), blk, 0, stream>>>(att, wp_t, 1024, 1024, 8,
        bp, x, x1);

    ln_kernel<<<MROWS, blk, 0, stream>>>(x1, g2, be2, h2);

    gemm256<2><<<dim3(512), dim3(512), 0, stream>>>(h2, w1_t, 4096, 1024, 16,
        b1, tbuf, nullptr, nullptr, nullptr);

    gemm_bt128<<<dim3(512), blk, 0, stream>>>(tbuf, w2_t, 1024, 4096, 8,
        b2, x1, out);
}